// Round 1
// baseline (5532.759 us; speedup 1.0000x reference)
//
#include <hip/hip_runtime.h>

// Fused 2-layer LSTM (H=50, D=5, T=512, B=4096) + linear head.
// grid=256 (1 block/CU), block=512 (8 waves, 2/SIMD), NB=16 batches/block.
// Weights transposed in LDS [k][200]; gate-lane layout: lane g in [0,200)
// computes gate g for 8 batches (acc in regs); h broadcast via uniform
// b128 LDS reads; c state lives in registers of the (b,j)-update threads.
// LDS total = 152 KB -> 1 block/CU.

#define NB 16
#define BLK 512
#define CH 32
#define LOG2E 1.44269504088896340736f

__device__ __forceinline__ float fexp2(float x) { return __builtin_amdgcn_exp2f(x); }
__device__ __forceinline__ float frcp(float x)  { return __builtin_amdgcn_rcpf(x); }

__global__ __launch_bounds__(512, 2) void lstm2_fused(
    const float* __restrict__ x,     // [4096][512][5]
    const float* __restrict__ Wih0,  // [200][5]
    const float* __restrict__ Whh0,  // [200][50]
    const float* __restrict__ bih0,  // [200]
    const float* __restrict__ bhh0,  // [200]
    const float* __restrict__ Wih1,  // [200][50]
    const float* __restrict__ Whh1,  // [200][50]
    const float* __restrict__ bih1,  // [200]
    const float* __restrict__ bhh1,  // [200]
    const float* __restrict__ Wlin,  // [1][50]
    const float* __restrict__ blin,  // [1]
    float* __restrict__ out)         // [4096]
{
    __shared__ __align__(16) float sWhh0[50 * 200];   // 40000 B
    __shared__ __align__(16) float sWc1[100 * 200];   // 80000 B (Wih1 rows 0-49, Whh1 rows 50-99)
    __shared__ __align__(16) float sH[NB * 100];      // 6400 B  (h0 in [0..49], h1 in [50..99])
    __shared__ __align__(16) float sAct[NB * 200];    // 12800 B (activated gates)
    __shared__ __align__(16) float sX[NB * CH * 8];   // 16384 B (x chunk, d padded 5->8)

    const int tid = threadIdx.x;
    const int bb0 = blockIdx.x * NB;

    // ---- stage weights transposed into LDS (one-time) ----
    for (int i = tid; i < 10000; i += BLK) {
        int g = i / 50, k = i - g * 50;
        sWhh0[k * 200 + g]        = Whh0[i];
        sWc1[k * 200 + g]         = Wih1[i];
        sWc1[(50 + k) * 200 + g]  = Whh1[i];
    }
    for (int i = tid; i < NB * 100; i += BLK) sH[i] = 0.0f;

    // ---- gate-lane identity ----
    const int g = tid & 255;              // gate id within half
    const int bbase = (tid >> 8) * 8;     // batches [bbase, bbase+8) (wave-uniform)
    const bool gate_active = (g < 200);

    float wih[5] = {0.f, 0.f, 0.f, 0.f, 0.f};
    float bias0g = 0.f, bias1g = 0.f;
    float aA = 1.f, bB = -LOG2E, cC = 0.f;   // act(x) = aA * rcp(1 + 2^(bB*x)) + cC
    if (gate_active) {
#pragma unroll
        for (int d = 0; d < 5; ++d) wih[d] = Wih0[g * 5 + d];
        bias0g = bih0[g] + bhh0[g];
        bias1g = bih1[g] + bhh1[g];
        if (g >= 100 && g < 150) { aA = 2.f; bB = -2.f * LOG2E; cC = -1.f; } // tanh gate
    }

    // ---- update-pair identity: pairs p in [0,800): b=p/50, j=p%50 ----
    const int p0 = tid;       const int b0p = p0 / 50, j0p = p0 - b0p * 50;
    const int p1 = BLK + tid; const int b1p = p1 / 50, j1p = p1 - b1p * 50;
    const bool up1 = (tid < NB * 50 - BLK);  // tid < 288
    float c0a = 0.f, c0b = 0.f, c1a = 0.f, c1b = 0.f;

    // ---- prefetch x chunk 0 into registers (5 dwords/thread, 2560 = 5*512 exact) ----
    float xr[5];
#pragma unroll
    for (int q = 0; q < 5; ++q) {
        int e = tid + q * BLK;
        int b = e / 160, r = e - b * 160;      // r = t_local*5 + d
        xr[q] = x[(size_t)(bb0 + b) * 2560 + r];
    }

    for (int t = 0; t < 512; ++t) {
        const int tt = t & (CH - 1);
        if (tt == 0) {
            __syncthreads();  // prior chunk fully consumed
#pragma unroll
            for (int q = 0; q < 5; ++q) {
                int e = tid + q * BLK;
                int b = e / 160, r = e - b * 160;
                int ts = r / 5, d = r - ts * 5;
                sX[b * (CH * 8) + ts * 8 + d] = xr[q];
            }
            if (t + CH < 512) {
#pragma unroll
                for (int q = 0; q < 5; ++q) {
                    int e = tid + q * BLK;
                    int b = e / 160, r = e - b * 160;
                    xr[q] = x[(size_t)(bb0 + b) * 2560 + (t + CH) * 5 + r];
                }
            }
            __syncthreads();
        }

        // ---- Phase A: layer-0 gates (pre-act -> activation -> sAct) ----
        if (gate_active) {
            float acc[8];
#pragma unroll
            for (int b = 0; b < 8; ++b) acc[b] = bias0g;
#pragma unroll
            for (int b = 0; b < 8; ++b) {
                const float* xp = &sX[(bbase + b) * (CH * 8) + tt * 8];
                float4 xv = *(const float4*)xp;
                float x4 = xp[4];
                acc[b] += wih[0] * xv.x + wih[1] * xv.y + wih[2] * xv.z +
                          wih[3] * xv.w + wih[4] * x4;
            }
#pragma unroll 4
            for (int k4 = 0; k4 < 12; ++k4) {
                float w0 = sWhh0[(k4 * 4 + 0) * 200 + g];
                float w1 = sWhh0[(k4 * 4 + 1) * 200 + g];
                float w2 = sWhh0[(k4 * 4 + 2) * 200 + g];
                float w3 = sWhh0[(k4 * 4 + 3) * 200 + g];
#pragma unroll
                for (int b = 0; b < 8; ++b) {
                    float4 hv = *(const float4*)&sH[(bbase + b) * 100 + k4 * 4];
                    acc[b] += w0 * hv.x + w1 * hv.y + w2 * hv.z + w3 * hv.w;
                }
            }
            {   // k = 48, 49 tail
                float w0 = sWhh0[48 * 200 + g];
                float w1 = sWhh0[49 * 200 + g];
#pragma unroll
                for (int b = 0; b < 8; ++b) {
                    float2 hv = *(const float2*)&sH[(bbase + b) * 100 + 48];
                    acc[b] += w0 * hv.x + w1 * hv.y;
                }
            }
#pragma unroll
            for (int b = 0; b < 8; ++b) {
                float s = frcp(1.f + fexp2(bB * acc[b]));
                sAct[(bbase + b) * 200 + g] = aA * s + cC;
            }
        }
        __syncthreads();

        // ---- Phase B: layer-0 cell/hidden update ----
        {
            float fi = sAct[b0p * 200 + j0p];
            float ff = sAct[b0p * 200 + j0p + 50];
            float fg = sAct[b0p * 200 + j0p + 100];
            float fo = sAct[b0p * 200 + j0p + 150];
            c0a = ff * c0a + fi * fg;
            float th = 2.f * frcp(1.f + fexp2(-2.f * LOG2E * c0a)) - 1.f;
            sH[b0p * 100 + j0p] = fo * th;
        }
        if (up1) {
            float fi = sAct[b1p * 200 + j1p];
            float ff = sAct[b1p * 200 + j1p + 50];
            float fg = sAct[b1p * 200 + j1p + 100];
            float fo = sAct[b1p * 200 + j1p + 150];
            c0b = ff * c0b + fi * fg;
            float th = 2.f * frcp(1.f + fexp2(-2.f * LOG2E * c0b)) - 1.f;
            sH[b1p * 100 + j1p] = fo * th;
        }
        __syncthreads();

        // ---- Phase C: layer-1 gates (input = [h0(t); h1(t-1)] = sH rows) ----
        if (gate_active) {
            float acc[8];
#pragma unroll
            for (int b = 0; b < 8; ++b) acc[b] = bias1g;
#pragma unroll 4
            for (int k4 = 0; k4 < 25; ++k4) {
                float w0 = sWc1[(k4 * 4 + 0) * 200 + g];
                float w1 = sWc1[(k4 * 4 + 1) * 200 + g];
                float w2 = sWc1[(k4 * 4 + 2) * 200 + g];
                float w3 = sWc1[(k4 * 4 + 3) * 200 + g];
#pragma unroll
                for (int b = 0; b < 8; ++b) {
                    float4 hv = *(const float4*)&sH[(bbase + b) * 100 + k4 * 4];
                    acc[b] += w0 * hv.x + w1 * hv.y + w2 * hv.z + w3 * hv.w;
                }
            }
#pragma unroll
            for (int b = 0; b < 8; ++b) {
                float s = frcp(1.f + fexp2(bB * acc[b]));
                sAct[(bbase + b) * 200 + g] = aA * s + cC;
            }
        }
        __syncthreads();

        // ---- Phase D: layer-1 cell/hidden update ----
        {
            float fi = sAct[b0p * 200 + j0p];
            float ff = sAct[b0p * 200 + j0p + 50];
            float fg = sAct[b0p * 200 + j0p + 100];
            float fo = sAct[b0p * 200 + j0p + 150];
            c1a = ff * c1a + fi * fg;
            float th = 2.f * frcp(1.f + fexp2(-2.f * LOG2E * c1a)) - 1.f;
            sH[b0p * 100 + 50 + j0p] = fo * th;
        }
        if (up1) {
            float fi = sAct[b1p * 200 + j1p];
            float ff = sAct[b1p * 200 + j1p + 50];
            float fg = sAct[b1p * 200 + j1p + 100];
            float fo = sAct[b1p * 200 + j1p + 150];
            c1b = ff * c1b + fi * fg;
            float th = 2.f * frcp(1.f + fexp2(-2.f * LOG2E * c1b)) - 1.f;
            sH[b1p * 100 + 50 + j1p] = fo * th;
        }
        __syncthreads();
    }

    // ---- linear head on final h1 ----
    if (tid < NB) {
        float s = blin[0];
#pragma unroll
        for (int j = 0; j < 50; ++j) s += Wlin[j] * sH[tid * 100 + 50 + j];
        out[bb0 + tid] = s;
    }
}

extern "C" void kernel_launch(void* const* d_in, const int* in_sizes, int n_in,
                              void* d_out, int out_size, void* d_ws, size_t ws_size,
                              hipStream_t stream) {
    (void)in_sizes; (void)n_in; (void)d_ws; (void)ws_size; (void)out_size;
    const float* x    = (const float*)d_in[0];
    const float* Wih0 = (const float*)d_in[1];
    const float* Whh0 = (const float*)d_in[2];
    const float* bih0 = (const float*)d_in[3];
    const float* bhh0 = (const float*)d_in[4];
    const float* Wih1 = (const float*)d_in[5];
    const float* Whh1 = (const float*)d_in[6];
    const float* bih1 = (const float*)d_in[7];
    const float* bhh1 = (const float*)d_in[8];
    const float* Wlin = (const float*)d_in[9];
    const float* blin = (const float*)d_in[10];

    lstm2_fused<<<dim3(256), dim3(512), 0, stream>>>(
        x, Wih0, Whh0, bih0, bhh0, Wih1, Whh1, bih1, bhh1, Wlin, blin,
        (float*)d_out);
}

// Round 2
// 923.399 us; speedup vs baseline: 5.9917x; 5.9917x over previous
//
#include <hip/hip_runtime.h>

// Fused 2-layer LSTM (H=50, D=5, T=512, B=4096) + linear head — MFMA version.
// grid=256 (1 block/CU), block=512 (8 waves), NB=16 batches/block.
// Gates[16x200] = H[16xK] @ W^T as mfma_f32_16x16x32_bf16 with hi/lo bf16
// split (3 MFMAs per K-step). Weights held in registers as B-frags all 512
// steps; h crosses LDS as bf16 hi/lo A-frags (per-lane-useful b128 reads).
// 8 waves x 2 N-tiles = 16 tile slots cover ceil(200/16)=13 real tiles.
// 3 barriers/step via split sG0/sG1 gate buffers.

#define NB 16
#define BLK 512
#define CH 32
#define LOG2E 1.44269504088896340736f

#define SA0 72    // shorts per row of layer-0 A (K=64 pad, +8 bank skew)
#define SA1 136   // shorts per row of layer-1 A (K=128 pad, +8 bank skew)
#define SG  210   // floats per row of gate buffers (bank-spread pad)
#define SXR 264   // floats per batch row of x chunk

typedef __attribute__((ext_vector_type(8))) short short8v;
typedef __attribute__((ext_vector_type(4))) float f32x4;

#define MFMA16(a, b, c) __builtin_amdgcn_mfma_f32_16x16x32_bf16((a), (b), (c), 0, 0, 0)

__device__ __forceinline__ float fexp2(float x) { return __builtin_amdgcn_exp2f(x); }
__device__ __forceinline__ float frcp(float x)  { return __builtin_amdgcn_rcpf(x); }
__device__ __forceinline__ unsigned short f2bf(float f) {
    unsigned u = __float_as_uint(f);
    return (unsigned short)((u + 0x7FFFu + ((u >> 16) & 1u)) >> 16);
}
__device__ __forceinline__ float bf2f(unsigned short h) {
    return __uint_as_float(((unsigned)h) << 16);
}
__device__ __forceinline__ float sigm(float x) { return frcp(1.f + fexp2(-LOG2E * x)); }
__device__ __forceinline__ float tanh_(float x) { return 2.f * frcp(1.f + fexp2(-2.f * LOG2E * x)) - 1.f; }

__global__ __launch_bounds__(512, 2) void lstm2_mfma(
    const float* __restrict__ x,     // [4096][512][5]
    const float* __restrict__ Wih0,  // [200][5]
    const float* __restrict__ Whh0,  // [200][50]
    const float* __restrict__ bih0,  // [200]
    const float* __restrict__ bhh0,  // [200]
    const float* __restrict__ Wih1,  // [200][50]
    const float* __restrict__ Whh1,  // [200][50]
    const float* __restrict__ bih1,  // [200]
    const float* __restrict__ bhh1,  // [200]
    const float* __restrict__ Wlin,  // [1][50]
    const float* __restrict__ blin,  // [1]
    float* __restrict__ out)         // [4096]
{
    __shared__ __align__(16) short sA0h[16 * SA0], sA0l[16 * SA0];  // h0 hi/lo
    __shared__ __align__(16) short sA1h[16 * SA1], sA1l[16 * SA1];  // [h0;h1] hi/lo
    __shared__ __align__(16) float sG0[16 * SG];                    // layer-0 gates
    __shared__ __align__(16) float sG1[16 * SG];                    // layer-1 gates
    __shared__ __align__(16) float sX[16 * SXR];                    // x chunk

    const int tid = threadIdx.x;
    const int w = tid >> 6, l = tid & 63, c = l >> 4, ln = l & 15;
    const int bb0 = blockIdx.x * NB;

    // ---- zero h state (incl. K-pad regions, never written again) ----
    for (int i = tid; i < 16 * SA0; i += BLK) { sA0h[i] = 0; sA0l[i] = 0; }
    for (int i = tid; i < 16 * SA1; i += BLK) { sA1h[i] = 0; sA1l[i] = 0; }

    // ---- per-lane tile identity: tiles tt = 2w+p, gate col g = tt*16+ln ----
    int gp[2]; bool gv[2];
    gp[0] = (2 * w + 0) * 16 + ln; gv[0] = gp[0] < 200;
    gp[1] = (2 * w + 1) * 16 + ln; gv[1] = gp[1] < 200;

    // ---- build B-frags in registers (held for all 512 steps) ----
    // k-slot convention (shared by A and B packing): k = 32*s + 8*c + j.
    short8v b0h[2][2], b0l[2][2];   // layer0: W = Whh0, K=50 (pad 64)
    short8v b1h[2][4], b1l[2][4];   // layer1: W = [Wih1 | Whh1], K=100 (pad 128)
    float w0v[2][5], bias0v[2], bias1v[2];
#pragma unroll
    for (int p = 0; p < 2; ++p) {
        const int g = gp[p]; const bool ok = gv[p];
#pragma unroll
        for (int s = 0; s < 2; ++s) {
            short8v th, tl;
#pragma unroll
            for (int j = 0; j < 8; ++j) {
                int k = 32 * s + 8 * c + j;
                float v = (ok && k < 50) ? Whh0[g * 50 + k] : 0.f;
                unsigned short hb = f2bf(v);
                th[j] = (short)hb; tl[j] = (short)f2bf(v - bf2f(hb));
            }
            b0h[p][s] = th; b0l[p][s] = tl;
        }
#pragma unroll
        for (int s = 0; s < 4; ++s) {
            short8v th, tl;
#pragma unroll
            for (int j = 0; j < 8; ++j) {
                int k = 32 * s + 8 * c + j;
                float v = 0.f;
                if (ok && k < 50)       v = Wih1[g * 50 + k];
                else if (ok && k < 100) v = Whh1[g * 50 + (k - 50)];
                unsigned short hb = f2bf(v);
                th[j] = (short)hb; tl[j] = (short)f2bf(v - bf2f(hb));
            }
            b1h[p][s] = th; b1l[p][s] = tl;
        }
#pragma unroll
        for (int d = 0; d < 5; ++d) w0v[p][d] = ok ? Wih0[g * 5 + d] : 0.f;
        bias0v[p] = ok ? (bih0[g] + bhh0[g]) : 0.f;
        bias1v[p] = ok ? (bih1[g] + bhh1[g]) : 0.f;
    }

    // ---- update-thread identity: pairs (b,j), slotA = tid, slotB = tid+512 ----
    const int bA = tid / 50, jA = tid - bA * 50;
    const int pb = tid + BLK;
    const int bB = pb / 50, jB = pb - bB * 50;
    const bool hasB = (tid < NB * 50 - BLK);   // tid < 288
    float c0A = 0.f, c0B = 0.f, c1A = 0.f, c1B = 0.f;

    // ---- prefetch x chunk 0 (5 dwords/thread, 2560 = 5*512 exact) ----
    float xr[5];
#pragma unroll
    for (int q = 0; q < 5; ++q) {
        int e = tid + q * BLK;
        int b = e / 160, r = e - b * 160;
        xr[q] = x[(size_t)(bb0 + b) * 2560 + r];
    }

    for (int t = 0; t < 512; ++t) {
        const int tt = t & (CH - 1);
        if (tt == 0) {
            // last sX readers were P0(t-1), already 3 barriers back -> safe
#pragma unroll
            for (int q = 0; q < 5; ++q) {
                int e = tid + q * BLK;
                int b = e / 160, r = e - b * 160;
                int ts = r / 5, d = r - ts * 5;
                sX[b * SXR + ts * 8 + d] = xr[q];
            }
            if (t + CH < 512) {
#pragma unroll
                for (int q = 0; q < 5; ++q) {
                    int e = tid + q * BLK;
                    int b = e / 160, r = e - b * 160;
                    xr[q] = x[(size_t)(bb0 + b) * 2560 + (t + CH) * 5 + r];
                }
            }
            __syncthreads();
        }

        // ================= P0: layer-0 MFMA =================
        {
            const int tt8 = tt * 8;
            float4 xv[4]; float x4[4];
#pragma unroll
            for (int r = 0; r < 4; ++r) {
                const float* xp_ = &sX[(4 * c + r) * SXR + tt8];
                xv[r] = *(const float4*)xp_; x4[r] = xp_[4];
            }
            f32x4 acc[2];
#pragma unroll
            for (int p = 0; p < 2; ++p) {
                f32x4 a;
#pragma unroll
                for (int r = 0; r < 4; ++r)
                    a[r] = bias0v[p] + w0v[p][0] * xv[r].x + w0v[p][1] * xv[r].y +
                           w0v[p][2] * xv[r].z + w0v[p][3] * xv[r].w + w0v[p][4] * x4[r];
                acc[p] = a;
            }
#pragma unroll
            for (int s = 0; s < 2; ++s) {
                short8v ah = *(const short8v*)&sA0h[ln * SA0 + 32 * s + 8 * c];
                short8v al = *(const short8v*)&sA0l[ln * SA0 + 32 * s + 8 * c];
#pragma unroll
                for (int p = 0; p < 2; ++p) {
                    acc[p] = MFMA16(ah, b0h[p][s], acc[p]);
                    acc[p] = MFMA16(ah, b0l[p][s], acc[p]);
                    acc[p] = MFMA16(al, b0h[p][s], acc[p]);
                }
            }
#pragma unroll
            for (int p = 0; p < 2; ++p) if (gv[p]) {
#pragma unroll
                for (int r = 0; r < 4; ++r)
                    sG0[(4 * c + r) * SG + gp[p]] = acc[p][r];
            }
        }
        __syncthreads();

        // ================= P1: layer-0 cell/hidden update =================
        {
            const float* gr = &sG0[bA * SG + jA];
            float gi = sigm(gr[0]), gf = sigm(gr[50]), gg = tanh_(gr[100]), go = sigm(gr[150]);
            c0A = gf * c0A + gi * gg;
            float h = go * tanh_(c0A);
            unsigned short hh = f2bf(h); unsigned short hl = f2bf(h - bf2f(hh));
            sA0h[bA * SA0 + jA] = (short)hh; sA0l[bA * SA0 + jA] = (short)hl;
            sA1h[bA * SA1 + jA] = (short)hh; sA1l[bA * SA1 + jA] = (short)hl;
        }
        if (hasB) {
            const float* gr = &sG0[bB * SG + jB];
            float gi = sigm(gr[0]), gf = sigm(gr[50]), gg = tanh_(gr[100]), go = sigm(gr[150]);
            c0B = gf * c0B + gi * gg;
            float h = go * tanh_(c0B);
            unsigned short hh = f2bf(h); unsigned short hl = f2bf(h - bf2f(hh));
            sA0h[bB * SA0 + jB] = (short)hh; sA0l[bB * SA0 + jB] = (short)hl;
            sA1h[bB * SA1 + jB] = (short)hh; sA1l[bB * SA1 + jB] = (short)hl;
        }
        __syncthreads();

        // ================= P2: layer-1 MFMA =================
        {
            f32x4 acc[2];
#pragma unroll
            for (int p = 0; p < 2; ++p) {
                f32x4 a;
#pragma unroll
                for (int r = 0; r < 4; ++r) a[r] = bias1v[p];
                acc[p] = a;
            }
#pragma unroll
            for (int s = 0; s < 4; ++s) {
                short8v ah = *(const short8v*)&sA1h[ln * SA1 + 32 * s + 8 * c];
                short8v al = *(const short8v*)&sA1l[ln * SA1 + 32 * s + 8 * c];
#pragma unroll
                for (int p = 0; p < 2; ++p) {
                    acc[p] = MFMA16(ah, b1h[p][s], acc[p]);
                    acc[p] = MFMA16(ah, b1l[p][s], acc[p]);
                    acc[p] = MFMA16(al, b1h[p][s], acc[p]);
                }
            }
#pragma unroll
            for (int p = 0; p < 2; ++p) if (gv[p]) {
#pragma unroll
                for (int r = 0; r < 4; ++r)
                    sG1[(4 * c + r) * SG + gp[p]] = acc[p][r];
            }
        }
        __syncthreads();

        // ================= P3: layer-1 cell/hidden update =================
        // (no trailing barrier: next readers of sA1[50+j] are P2(t+1),
        //  separated by the P0- and P1-end barriers)
        {
            const float* gr = &sG1[bA * SG + jA];
            float gi = sigm(gr[0]), gf = sigm(gr[50]), gg = tanh_(gr[100]), go = sigm(gr[150]);
            c1A = gf * c1A + gi * gg;
            float h = go * tanh_(c1A);
            unsigned short hh = f2bf(h); unsigned short hl = f2bf(h - bf2f(hh));
            sA1h[bA * SA1 + 50 + jA] = (short)hh; sA1l[bA * SA1 + 50 + jA] = (short)hl;
        }
        if (hasB) {
            const float* gr = &sG1[bB * SG + jB];
            float gi = sigm(gr[0]), gf = sigm(gr[50]), gg = tanh_(gr[100]), go = sigm(gr[150]);
            c1B = gf * c1B + gi * gg;
            float h = go * tanh_(c1B);
            unsigned short hh = f2bf(h); unsigned short hl = f2bf(h - bf2f(hh));
            sA1h[bB * SA1 + 50 + jB] = (short)hh; sA1l[bB * SA1 + 50 + jB] = (short)hl;
        }
        __syncthreads();
    }

    // ---- linear head on final h1 (reconstruct fp32 as hi+lo) ----
    if (tid < NB) {
        float s = blin[0];
#pragma unroll
        for (int j = 0; j < 50; ++j)
            s += Wlin[j] * (bf2f((unsigned short)sA1h[tid * SA1 + 50 + j]) +
                            bf2f((unsigned short)sA1l[tid * SA1 + 50 + j]));
        out[bb0 + tid] = s;
    }
}

extern "C" void kernel_launch(void* const* d_in, const int* in_sizes, int n_in,
                              void* d_out, int out_size, void* d_ws, size_t ws_size,
                              hipStream_t stream) {
    (void)in_sizes; (void)n_in; (void)d_ws; (void)ws_size; (void)out_size;
    const float* x    = (const float*)d_in[0];
    const float* Wih0 = (const float*)d_in[1];
    const float* Whh0 = (const float*)d_in[2];
    const float* bih0 = (const float*)d_in[3];
    const float* bhh0 = (const float*)d_in[4];
    const float* Wih1 = (const float*)d_in[5];
    const float* Whh1 = (const float*)d_in[6];
    const float* bih1 = (const float*)d_in[7];
    const float* bhh1 = (const float*)d_in[8];
    const float* Wlin = (const float*)d_in[9];
    const float* blin = (const float*)d_in[10];

    lstm2_mfma<<<dim3(256), dim3(512), 0, stream>>>(
        x, Wih0, Whh0, bih0, bhh0, Wih1, Whh1, bih1, bhh1, Wlin, blin,
        (float*)d_out);
}

// Round 3
// 635.008 us; speedup vs baseline: 8.7129x; 1.4542x over previous
//
#include <hip/hip_runtime.h>

// Fused 2-layer LSTM (H=50, D=5, T=512, B=4096) + linear head — pipelined MFMA.
// grid=256 (1 block/CU), block=512 (8 waves), NB=16 batches/block.
// Waves 0-3: layer-0 step t. Waves 4-7: layer-1 step t-1 (independent) -> ONE
// barrier per tick, double-buffered h arrays. Each wave computes 4 N-tiles
// whose columns are gates {j,50+j,100+j,150+j}, j=16*wl+ln -> i,f,g,o for one
// j land in ONE lane => cell state + activations fully register-resident.
// x-projection folded into MFMA via A-slots k=50..54 (B-rows = Wih0).
// bf16 hi/lo 3-MFMA split (ah*bh + ah*bl + al*bh) for fp32-grade accuracy.

#define NB 16
#define BLK 512
#define TT 512
#define LOG2E 1.44269504088896340736f
#define SA0 72    // shorts per row, layer-0 A (K=64 pad, skewed stride)
#define SA1 136   // shorts per row, layer-1 A (K=128 pad, skewed stride)
#define SXR 264   // floats per batch row of x chunk

typedef __attribute__((ext_vector_type(8))) short short8v;
typedef __attribute__((ext_vector_type(4))) float f32x4;

#define MFMA16(a, b, c) __builtin_amdgcn_mfma_f32_16x16x32_bf16((a), (b), (c), 0, 0, 0)

__device__ __forceinline__ float fexp2(float x) { return __builtin_amdgcn_exp2f(x); }
__device__ __forceinline__ float frcp(float x)  { return __builtin_amdgcn_rcpf(x); }
__device__ __forceinline__ unsigned short f2bf(float f) {
    unsigned u = __float_as_uint(f);
    return (unsigned short)((u + 0x7FFFu + ((u >> 16) & 1u)) >> 16);
}
__device__ __forceinline__ float bf2f(unsigned short h) {
    return __uint_as_float(((unsigned)h) << 16);
}
__device__ __forceinline__ float sigm(float x) { return frcp(1.f + fexp2(-LOG2E * x)); }
__device__ __forceinline__ float tanh_(float x) { return 2.f * frcp(1.f + fexp2(-2.f * LOG2E * x)) - 1.f; }

__global__ __launch_bounds__(512, 2) void lstm2_pipe(
    const float* __restrict__ x,     // [4096][512][5]
    const float* __restrict__ Wih0,  // [200][5]
    const float* __restrict__ Whh0,  // [200][50]
    const float* __restrict__ bih0,  // [200]
    const float* __restrict__ bhh0,  // [200]
    const float* __restrict__ Wih1,  // [200][50]
    const float* __restrict__ Whh1,  // [200][50]
    const float* __restrict__ bih1,  // [200]
    const float* __restrict__ bhh1,  // [200]
    const float* __restrict__ Wlin,  // [1][50]
    const float* __restrict__ blin,  // [1]
    float* __restrict__ out)         // [4096]
{
    // double-buffered A operands (bf16 hi/lo). A0: [h0(k=0..49) | x(k=50..54)]
    // A1: [h0(k=0..49) | h1(k=50..99)]; pad rows stay zero forever.
    __shared__ __align__(16) short sA0h[2][16 * SA0], sA0l[2][16 * SA0];
    __shared__ __align__(16) short sA1h[2][16 * SA1], sA1l[2][16 * SA1];
    __shared__ __align__(16) float sX[16 * SXR];   // 32-tick x chunk

    const int tid = threadIdx.x;
    const int w = tid >> 6, l = tid & 63, c = l >> 4, ln = l & 15;
    const int grp = w >> 2, wl = w & 3;
    const int bb0 = blockIdx.x * NB;
    const int j = 16 * wl + ln;
    const bool jv = (j < 50);

    // ---- zero-init all A buffers (h slots, x slots, pads) ----
    for (int i = tid; i < 2 * 16 * SA0; i += BLK) { (&sA0h[0][0])[i] = 0; (&sA0l[0][0])[i] = 0; }
    for (int i = tid; i < 2 * 16 * SA1; i += BLK) { (&sA1h[0][0])[i] = 0; (&sA1l[0][0])[i] = 0; }

    // ---- B-frags in registers for all 512 steps (shared storage, 128 VGPR) ----
    // k-slot convention (A and B identical): k = 32*s + 8*c + jj.
    short8v bh[4][4], bl[4][4];
    float bias[4];
    if (grp == 0) {
#pragma unroll
        for (int p = 0; p < 4; ++p) {
            const int g = p * 50 + j;
#pragma unroll
            for (int s = 0; s < 4; ++s) {
                short8v th, tl;
#pragma unroll
                for (int jj = 0; jj < 8; ++jj) {
                    int k = 32 * s + 8 * c + jj;
                    float v = 0.f;
                    if (jv) {
                        if (k < 50)      v = Whh0[g * 50 + k];
                        else if (k < 55) v = Wih0[g * 5 + (k - 50)];
                    }
                    unsigned short hb = f2bf(v);
                    th[jj] = (short)hb; tl[jj] = (short)f2bf(v - bf2f(hb));
                }
                bh[p][s] = th; bl[p][s] = tl;
            }
            bias[p] = jv ? (bih0[g] + bhh0[g]) : 0.f;
        }
    } else {
#pragma unroll
        for (int p = 0; p < 4; ++p) {
            const int g = p * 50 + j;
#pragma unroll
            for (int s = 0; s < 4; ++s) {
                short8v th, tl;
#pragma unroll
                for (int jj = 0; jj < 8; ++jj) {
                    int k = 32 * s + 8 * c + jj;
                    float v = 0.f;
                    if (jv) {
                        if (k < 50)       v = Wih1[g * 50 + k];
                        else if (k < 100) v = Whh1[g * 50 + (k - 50)];
                    }
                    unsigned short hb = f2bf(v);
                    th[jj] = (short)hb; tl[jj] = (short)f2bf(v - bf2f(hb));
                }
                bh[p][s] = th; bl[p][s] = tl;
            }
            bias[p] = jv ? (bih1[g] + bhh1[g]) : 0.f;
        }
    }

    float cst[4] = {0.f, 0.f, 0.f, 0.f};   // cell state: batches 4c+r, own j

    // ---- chunk 0 -> regs -> sX; prefetch chunk 1 ----
    float xr[5];
#pragma unroll
    for (int q = 0; q < 5; ++q) {
        int e = tid + q * BLK, b = e / 160, r = e - b * 160;
        xr[q] = x[(size_t)(bb0 + b) * 2560 + r];
    }
#pragma unroll
    for (int q = 0; q < 5; ++q) {
        int e = tid + q * BLK, b = e / 160, r = e - b * 160;
        int ts = r / 5, d = r - ts * 5;
        sX[b * SXR + ts * 8 + d] = xr[q];
    }
#pragma unroll
    for (int q = 0; q < 5; ++q) {
        int e = tid + q * BLK, b = e / 160, r = e - b * 160;
        xr[q] = x[(size_t)(bb0 + b) * 2560 + 160 + r];
    }
    __syncthreads();   // zero-init + sX visible before x(0) write / tick 0

    // x(0) -> buf[1] slots k=50..54 (tick 0 reads buf[1])
    if (tid < 80) {
        int b = tid / 5, d = tid - 5 * b;
        float v = x[(size_t)(bb0 + b) * 2560 + d];
        unsigned short hb = f2bf(v);
        sA0h[1][b * SA0 + 50 + d] = (short)hb;
        sA0l[1][b * SA0 + 50 + d] = (short)f2bf(v - bf2f(hb));
    }
    __syncthreads();

    for (int t = 0; t <= TT; ++t) {
        const int rb = (t + 1) & 1;   // read buffer  = (t-1)&1
        const int wb = t & 1;         // write buffer

        // ---- chunk staging at t = 31, 63, ..., 479 (covers ticks t+1..t+32) ----
        if ((t & 31) == 31 && t < TT - 1) {
#pragma unroll
            for (int q = 0; q < 5; ++q) {
                int e = tid + q * BLK, b = e / 160, r = e - b * 160;
                int ts = r / 5, d = r - ts * 5;
                sX[b * SXR + ts * 8 + d] = xr[q];
            }
            if (t + 33 < TT) {
#pragma unroll
                for (int q = 0; q < 5; ++q) {
                    int e = tid + q * BLK, b = e / 160, r = e - b * 160;
                    xr[q] = x[(size_t)(bb0 + b) * 2560 + (size_t)(t + 33) * 5 + r];
                }
            }
            __syncthreads();
        }

        // ---- x(t+1) -> buf[wb] slots k=50..54 (read next tick; overlaps MFMA) ----
        if (t < TT - 1 && tid < 80) {
            int b = tid / 5, d = tid - 5 * b, tl1 = (t + 1) & 31;
            float v = sX[b * SXR + tl1 * 8 + d];
            unsigned short hb = f2bf(v);
            sA0h[wb][b * SA0 + 50 + d] = (short)hb;
            sA0l[wb][b * SA0 + 50 + d] = (short)f2bf(v - bf2f(hb));
        }

        if (grp == 0) {
            // ======== layer-0, step t ========
            if (t < TT) {
                f32x4 acc[4];
#pragma unroll
                for (int p = 0; p < 4; ++p) {
                    f32x4 a; a[0] = bias[p]; a[1] = bias[p]; a[2] = bias[p]; a[3] = bias[p];
                    acc[p] = a;
                }
#pragma unroll
                for (int s = 0; s < 2; ++s) {
                    short8v ah = *(const short8v*)&sA0h[rb][ln * SA0 + 32 * s + 8 * c];
                    short8v al = *(const short8v*)&sA0l[rb][ln * SA0 + 32 * s + 8 * c];
#pragma unroll
                    for (int p = 0; p < 4; ++p) {
                        acc[p] = MFMA16(ah, bh[p][s], acc[p]);
                        acc[p] = MFMA16(ah, bl[p][s], acc[p]);
                        acc[p] = MFMA16(al, bh[p][s], acc[p]);
                    }
                }
                if (jv) {
#pragma unroll
                    for (int r = 0; r < 4; ++r) {
                        float gi = sigm(acc[0][r]);
                        float gf = sigm(acc[1][r]);
                        float gg = tanh_(acc[2][r]);
                        float go = sigm(acc[3][r]);
                        cst[r] = gf * cst[r] + gi * gg;
                        float h = go * tanh_(cst[r]);
                        unsigned short hh = f2bf(h);
                        unsigned short hl = f2bf(h - bf2f(hh));
                        const int row = 4 * c + r;
                        sA0h[wb][row * SA0 + j] = (short)hh;
                        sA0l[wb][row * SA0 + j] = (short)hl;
                        sA1h[wb][row * SA1 + j] = (short)hh;
                        sA1l[wb][row * SA1 + j] = (short)hl;
                    }
                }
            }
        } else {
            // ======== layer-1, step t-1 ========
            if (t > 0) {
                f32x4 acc[4];
#pragma unroll
                for (int p = 0; p < 4; ++p) {
                    f32x4 a; a[0] = bias[p]; a[1] = bias[p]; a[2] = bias[p]; a[3] = bias[p];
                    acc[p] = a;
                }
#pragma unroll
                for (int s = 0; s < 4; ++s) {
                    short8v ah = *(const short8v*)&sA1h[rb][ln * SA1 + 32 * s + 8 * c];
                    short8v al = *(const short8v*)&sA1l[rb][ln * SA1 + 32 * s + 8 * c];
#pragma unroll
                    for (int p = 0; p < 4; ++p) {
                        acc[p] = MFMA16(ah, bh[p][s], acc[p]);
                        acc[p] = MFMA16(ah, bl[p][s], acc[p]);
                        acc[p] = MFMA16(al, bh[p][s], acc[p]);
                    }
                }
                if (jv) {
#pragma unroll
                    for (int r = 0; r < 4; ++r) {
                        float gi = sigm(acc[0][r]);
                        float gf = sigm(acc[1][r]);
                        float gg = tanh_(acc[2][r]);
                        float go = sigm(acc[3][r]);
                        cst[r] = gf * cst[r] + gi * gg;
                        float h = go * tanh_(cst[r]);
                        unsigned short hh = f2bf(h);
                        unsigned short hl = f2bf(h - bf2f(hh));
                        const int row = 4 * c + r;
                        sA1h[wb][row * SA1 + 50 + j] = (short)hh;
                        sA1l[wb][row * SA1 + 50 + j] = (short)hl;
                    }
                }
            }
        }
        __syncthreads();
    }

    // ---- linear head on final h1(511) (in buf[0], k=50..99) ----
    if (tid < NB) {
        float s = blin[0];
#pragma unroll
        for (int jj = 0; jj < 50; ++jj)
            s += Wlin[jj] * (bf2f((unsigned short)sA1h[0][tid * SA1 + 50 + jj]) +
                             bf2f((unsigned short)sA1l[0][tid * SA1 + 50 + jj]));
        out[bb0 + tid] = s;
    }
}

extern "C" void kernel_launch(void* const* d_in, const int* in_sizes, int n_in,
                              void* d_out, int out_size, void* d_ws, size_t ws_size,
                              hipStream_t stream) {
    (void)in_sizes; (void)n_in; (void)d_ws; (void)ws_size; (void)out_size;
    const float* x    = (const float*)d_in[0];
    const float* Wih0 = (const float*)d_in[1];
    const float* Whh0 = (const float*)d_in[2];
    const float* bih0 = (const float*)d_in[3];
    const float* bhh0 = (const float*)d_in[4];
    const float* Wih1 = (const float*)d_in[5];
    const float* Whh1 = (const float*)d_in[6];
    const float* bih1 = (const float*)d_in[7];
    const float* bhh1 = (const float*)d_in[8];
    const float* Wlin = (const float*)d_in[9];
    const float* blin = (const float*)d_in[10];

    lstm2_pipe<<<dim3(256), dim3(512), 0, stream>>>(
        x, Wih0, Whh0, bih0, bhh0, Wih1, Whh1, bih1, bhh1, Wlin, blin,
        (float*)d_out);
}

// Round 4
// 514.143 us; speedup vs baseline: 10.7611x; 1.2351x over previous
//
#include <hip/hip_runtime.h>

// Fused 2-layer LSTM (H=50, D=5, T=512, B=4096) + linear head — f16 MFMA v2.
// grid=256 (1 block/CU), block=512 (8 waves), NB=16 batches/block.
// Waves 0-3: layer-0 step t; waves 4-7: layer-1 step t-1; ONE barrier/tick.
// A operands single f16 (h quant 2^-12); B weights f16 hi/lo with lo
// pre-scaled by 2^11 (avoids f16 denormals), separate accumulator, one
// combine FMA -> effective 22-bit weights, 2 MFMAs per K-slot (was 3).
// Layer-1 reads h0 directly from sA0 (s=0,1; B rows 50..63 zero over x
// slots) and h1 from sA1 (s=2,3) -> h written once, pack = 1 cvt + 1 write.

#define NB 16
#define BLK 512
#define TT 512
#define LOG2E 1.44269504088896340736f
#define SA 72            // _Float16 per row (K=64 pad, 144 B skewed stride)
#define SXR 264          // floats per batch row of x chunk
#define LOSCALE 2048.0f
#define INVLOSCALE (1.0f/2048.0f)

typedef _Float16 half8 __attribute__((ext_vector_type(8)));
typedef __attribute__((ext_vector_type(4))) float f32x4;

#define MFMAH(a, b, c) __builtin_amdgcn_mfma_f32_16x16x32_f16((a), (b), (c), 0, 0, 0)

__device__ __forceinline__ float fexp2(float x) { return __builtin_amdgcn_exp2f(x); }
__device__ __forceinline__ float frcp(float x)  { return __builtin_amdgcn_rcpf(x); }
__device__ __forceinline__ float sigm(float x)  { return frcp(1.f + fexp2(-LOG2E * x)); }
__device__ __forceinline__ float tanh_(float x) { return 2.f * frcp(1.f + fexp2(-2.f * LOG2E * x)) - 1.f; }

__global__ __launch_bounds__(512, 2) void lstm2_f16(
    const float* __restrict__ x,     // [4096][512][5]
    const float* __restrict__ Wih0,  // [200][5]
    const float* __restrict__ Whh0,  // [200][50]
    const float* __restrict__ bih0,  // [200]
    const float* __restrict__ bhh0,  // [200]
    const float* __restrict__ Wih1,  // [200][50]
    const float* __restrict__ Whh1,  // [200][50]
    const float* __restrict__ bih1,  // [200]
    const float* __restrict__ bhh1,  // [200]
    const float* __restrict__ Wlin,  // [1][50]
    const float* __restrict__ blin,  // [1]
    float* __restrict__ out)         // [4096]
{
    // A buffers, double-buffered. sA0 row: [h0 k=0..49 | x k=50..54 | pad]
    // sA1 row: [h1 k=0..49 | pad]. Pads zeroed once, never rewritten.
    __shared__ __align__(16) _Float16 sA0[2][16 * SA];
    __shared__ __align__(16) _Float16 sA1[2][16 * SA];
    __shared__ __align__(16) float sX[16 * SXR];

    const int tid = threadIdx.x;
    const int w = tid >> 6, l = tid & 63, c = l >> 4, ln = l & 15;
    const int grp = w >> 2, wl = w & 3;
    const int bb0 = blockIdx.x * NB;
    const int j = 16 * wl + ln;
    const bool jv = (j < 50);

    for (int i = tid; i < 2 * 16 * SA; i += BLK) { (&sA0[0][0])[i] = (_Float16)0.f; (&sA1[0][0])[i] = (_Float16)0.f; }

    // ---- B-frags (f16 hi + scaled lo) in registers for all 512 steps ----
    // unified k in [0,128): k<64 -> sA0 semantics (h0, x), k>=64 -> sA1 (h1).
    half8 bh[4][4], bl[4][4];
    float bias[4];
#pragma unroll
    for (int p = 0; p < 4; ++p) {
        const int g = p * 50 + j;
#pragma unroll
        for (int s = 0; s < 4; ++s) {
            half8 th, tl;
#pragma unroll
            for (int jj = 0; jj < 8; ++jj) {
                int k = 32 * s + 8 * c + jj;
                float v = 0.f;
                if (jv) {
                    if (grp == 0) {
                        if (k < 50)      v = Whh0[g * 50 + k];
                        else if (k < 55) v = Wih0[g * 5 + (k - 50)];
                    } else {
                        if (k < 50)                 v = Wih1[g * 50 + k];
                        else if (k >= 64 && k < 114) v = Whh1[g * 50 + (k - 64)];
                    }
                }
                _Float16 hi = (_Float16)v;
                _Float16 lo = (_Float16)((v - (float)hi) * LOSCALE);
                th[jj] = hi; tl[jj] = lo;
            }
            bh[p][s] = th; bl[p][s] = tl;
        }
        bias[p] = jv ? ((grp == 0) ? (bih0[g] + bhh0[g]) : (bih1[g] + bhh1[g])) : 0.f;
    }

    float cst[4] = {0.f, 0.f, 0.f, 0.f};   // cell state: batches 4c+r, own j

    // ---- x chunk 0 -> sX; prefetch chunk 1 ----
    float xr[5];
#pragma unroll
    for (int q = 0; q < 5; ++q) {
        int e = tid + q * BLK, b = e / 160, r = e - b * 160;
        xr[q] = x[(size_t)(bb0 + b) * 2560 + r];
    }
#pragma unroll
    for (int q = 0; q < 5; ++q) {
        int e = tid + q * BLK, b = e / 160, r = e - b * 160;
        int ts = r / 5, d = r - ts * 5;
        sX[b * SXR + ts * 8 + d] = xr[q];
    }
#pragma unroll
    for (int q = 0; q < 5; ++q) {
        int e = tid + q * BLK, b = e / 160, r = e - b * 160;
        xr[q] = x[(size_t)(bb0 + b) * 2560 + 160 + r];
    }
    __syncthreads();   // zero-init + sX visible

    if (tid < 80) {    // x(0) -> buf[1] (tick 0 reads rb=1)
        int b = tid / 5, d = tid - 5 * b;
        sA0[1][b * SA + 50 + d] = (_Float16)x[(size_t)(bb0 + b) * 2560 + d];
    }
    __syncthreads();

    for (int t = 0; t <= TT; ++t) {
        const int rb = (t + 1) & 1;
        const int wb = t & 1;

        if ((t & 31) == 31 && t < TT - 1) {
#pragma unroll
            for (int q = 0; q < 5; ++q) {
                int e = tid + q * BLK, b = e / 160, r = e - b * 160;
                int ts = r / 5, d = r - ts * 5;
                sX[b * SXR + ts * 8 + d] = xr[q];
            }
            if (t + 33 < TT) {
#pragma unroll
                for (int q = 0; q < 5; ++q) {
                    int e = tid + q * BLK, b = e / 160, r = e - b * 160;
                    xr[q] = x[(size_t)(bb0 + b) * 2560 + (size_t)(t + 33) * 5 + r];
                }
            }
            __syncthreads();
        }

        // x(t+1) -> buf[wb] x-slots (read next tick; overlaps MFMA below)
        if (t < TT - 1 && tid < 80) {
            int b = tid / 5, d = tid - 5 * b, tl1 = (t + 1) & 31;
            sA0[wb][b * SA + 50 + d] = (_Float16)sX[b * SXR + tl1 * 8 + d];
        }

        if (grp == 0) {
            // ======== layer-0, step t ========
            if (t < TT) {
                f32x4 ah[4], al[4];
#pragma unroll
                for (int p = 0; p < 4; ++p) {
                    f32x4 a; a[0] = bias[p]; a[1] = bias[p]; a[2] = bias[p]; a[3] = bias[p];
                    ah[p] = a;
                    f32x4 z; z[0] = 0.f; z[1] = 0.f; z[2] = 0.f; z[3] = 0.f;
                    al[p] = z;
                }
#pragma unroll
                for (int s = 0; s < 2; ++s) {
                    half8 a = *(const half8*)&sA0[rb][ln * SA + 32 * s + 8 * c];
#pragma unroll
                    for (int p = 0; p < 4; ++p) {
                        ah[p] = MFMAH(a, bh[p][s], ah[p]);
                        al[p] = MFMAH(a, bl[p][s], al[p]);
                    }
                }
                if (jv) {
#pragma unroll
                    for (int r = 0; r < 4; ++r) {
                        float ti = ah[0][r] + al[0][r] * INVLOSCALE;
                        float tf = ah[1][r] + al[1][r] * INVLOSCALE;
                        float tg = ah[2][r] + al[2][r] * INVLOSCALE;
                        float to = ah[3][r] + al[3][r] * INVLOSCALE;
                        float gi = sigm(ti), gf = sigm(tf), gg = tanh_(tg), go = sigm(to);
                        cst[r] = gf * cst[r] + gi * gg;
                        float h = go * tanh_(cst[r]);
                        sA0[wb][(4 * c + r) * SA + j] = (_Float16)h;
                    }
                }
            }
        } else {
            // ======== layer-1, step t-1 ========
            if (t > 0) {
                f32x4 ah[4], al[4];
#pragma unroll
                for (int p = 0; p < 4; ++p) {
                    f32x4 a; a[0] = bias[p]; a[1] = bias[p]; a[2] = bias[p]; a[3] = bias[p];
                    ah[p] = a;
                    f32x4 z; z[0] = 0.f; z[1] = 0.f; z[2] = 0.f; z[3] = 0.f;
                    al[p] = z;
                }
#pragma unroll
                for (int s = 0; s < 4; ++s) {
                    half8 a = (s < 2)
                        ? *(const half8*)&sA0[rb][ln * SA + 32 * s + 8 * c]
                        : *(const half8*)&sA1[rb][ln * SA + 32 * (s - 2) + 8 * c];
#pragma unroll
                    for (int p = 0; p < 4; ++p) {
                        ah[p] = MFMAH(a, bh[p][s], ah[p]);
                        al[p] = MFMAH(a, bl[p][s], al[p]);
                    }
                }
                if (jv) {
#pragma unroll
                    for (int r = 0; r < 4; ++r) {
                        float ti = ah[0][r] + al[0][r] * INVLOSCALE;
                        float tf = ah[1][r] + al[1][r] * INVLOSCALE;
                        float tg = ah[2][r] + al[2][r] * INVLOSCALE;
                        float to = ah[3][r] + al[3][r] * INVLOSCALE;
                        float gi = sigm(ti), gf = sigm(tf), gg = tanh_(tg), go = sigm(to);
                        cst[r] = gf * cst[r] + gi * gg;
                        float h = go * tanh_(cst[r]);
                        sA1[wb][(4 * c + r) * SA + j] = (_Float16)h;
                    }
                }
            }
        }
        __syncthreads();
    }

    // ---- linear head on final h1(511) (tick 512 wrote buf[0]) ----
    if (tid < NB) {
        float s = blin[0];
#pragma unroll
        for (int jj = 0; jj < 50; ++jj)
            s += Wlin[jj] * (float)sA1[0][tid * SA + jj];
        out[bb0 + tid] = s;
    }
}

extern "C" void kernel_launch(void* const* d_in, const int* in_sizes, int n_in,
                              void* d_out, int out_size, void* d_ws, size_t ws_size,
                              hipStream_t stream) {
    (void)in_sizes; (void)n_in; (void)d_ws; (void)ws_size; (void)out_size;
    const float* x    = (const float*)d_in[0];
    const float* Wih0 = (const float*)d_in[1];
    const float* Whh0 = (const float*)d_in[2];
    const float* bih0 = (const float*)d_in[3];
    const float* bhh0 = (const float*)d_in[4];
    const float* Wih1 = (const float*)d_in[5];
    const float* Whh1 = (const float*)d_in[6];
    const float* bih1 = (const float*)d_in[7];
    const float* bhh1 = (const float*)d_in[8];
    const float* Wlin = (const float*)d_in[9];
    const float* blin = (const float*)d_in[10];

    lstm2_f16<<<dim3(256), dim3(512), 0, stream>>>(
        x, Wih0, Whh0, bih0, bhh0, Wih1, Whh1, bih1, bhh1, Wlin, blin,
        (float*)d_out);
}